// Round 4
// baseline (324.704 us; speedup 1.0000x reference)
//
#include <hip/hip_runtime.h>
#include <hip/hip_fp16.h>

#define NN 2048

typedef _Float16 f16x8 __attribute__((ext_vector_type(8)));
typedef float f32x16 __attribute__((ext_vector_type(16)));

// ---------------------------------------------------------------------------
// Prep: proj = A@Wp.T + bp  (2048x32), then
//       pa'  = proj@Wa.T + b1  (f16, b1 folded),  pb = proj@Wb.T (f16)
// ---------------------------------------------------------------------------
__global__ __launch_bounds__(256) void prep_kernel(
    const float* __restrict__ A, const float* __restrict__ Wp,
    const float* __restrict__ bp, const float* __restrict__ W1,
    const float* __restrict__ b1,
    _Float16* __restrict__ pa, _Float16* __restrict__ pb)
{
    __shared__ float projLDS[8][32];
    const int t = threadIdx.x;
    const int rl = t >> 5;        // local row 0..7
    const int k  = t & 31;        // output unit 0..31
    const int row = blockIdx.x * 8 + rl;

    const float4* xa = (const float4*)(A + row * 64);
    const float4* wp = (const float4*)(Wp + k * 64);
    float acc = bp[k];
#pragma unroll
    for (int m = 0; m < 16; ++m) {
        float4 xv = xa[m], wv = wp[m];
        acc += xv.x * wv.x + xv.y * wv.y + xv.z * wv.z + xv.w * wv.w;
    }
    projLDS[rl][k] = acc;
    __syncthreads();

    const float4* w1a = (const float4*)(W1 + k * 64);        // m = 0..31
    const float4* w1b = (const float4*)(W1 + k * 64 + 32);   // m = 32..63
    const float4* pr  = (const float4*)(projLDS[rl]);
    float sa = b1[k], sb = 0.f;
#pragma unroll
    for (int m = 0; m < 8; ++m) {
        float4 p = pr[m], wa = w1a[m], wb = w1b[m];
        sa += p.x * wa.x + p.y * wa.y + p.z * wa.z + p.w * wa.w;
        sb += p.x * wb.x + p.y * wb.y + p.z * wb.z + p.w * wb.w;
    }
    pa[row * 32 + k] = (_Float16)sa;
    pb[row * 32 + k] = (_Float16)sb;
}

// ---------------------------------------------------------------------------
// Main: one wave computes a 32i x 32j output tile; 4 waves/block share i0.
// (byte-identical to R3 — control for the probe experiment)
// ---------------------------------------------------------------------------
__global__ __launch_bounds__(256) void sim_kernel(
    const _Float16* __restrict__ pa, const _Float16* __restrict__ pb,
    const float* __restrict__ W2, const float* __restrict__ b2,
    const float* __restrict__ W3, const float* __restrict__ b3,
    float* __restrict__ out)
{
    __shared__ _Float16 paLDS[32 * 32];
    const int t    = threadIdx.x;
    const int lane = t & 63;
    const int wid  = t >> 6;
    const int i0 = (blockIdx.x >> 4) * 32;
    const int jb = (((blockIdx.x & 15) << 2) + wid) * 32;
    const int p  = lane & 31;
    const int g  = lane >> 5;

    ((uint2*)paLDS)[t] = ((const uint2*)(pa + (size_t)i0 * 32))[t];

    const _Float16* pbrow = pb + (size_t)(jb + p) * 32;
    f16x8 pblo = *(const f16x8*)(pbrow + g * 8);
    f16x8 pbhi = *(const f16x8*)(pbrow + 16 + g * 8);

    f16x8 w2lo = {};
    f16x8 w2hi = {};
    if (p < 16) {
        const float* w2r = W2 + p * 32;
#pragma unroll
        for (int e = 0; e < 8; ++e) {
            w2lo[e] = (_Float16)w2r[g * 8 + e];
            w2hi[e] = (_Float16)w2r[16 + g * 8 + e];
        }
    }

    float w3r[8];
    f32x16 cinit;
#pragma unroll
    for (int r = 0; r < 4; ++r) {
        w3r[r]       = W3[4 * g + r];
        w3r[4 + r]   = W3[8 + 4 * g + r];
        cinit[r]     = b2[4 * g + r];
        cinit[4 + r] = b2[8 + 4 * g + r];
    }
#pragma unroll
    for (int r = 8; r < 16; ++r) cinit[r] = 0.f;

    const float b3v = b3[0];
    const f16x8 zero = {};
    const int j = jb + p;

    __syncthreads();

#pragma unroll 4
    for (int ii = 0; ii < 32; ++ii) {
        const int i = i0 + ii;
        f16x8 alo = *(const f16x8*)&paLDS[ii * 32 + g * 8];
        f16x8 ahi = *(const f16x8*)&paLDS[ii * 32 + 16 + g * 8];
        f16x8 h1lo = __builtin_elementwise_max(alo + pblo, zero);
        f16x8 h1hi = __builtin_elementwise_max(ahi + pbhi, zero);

        f32x16 d = __builtin_amdgcn_mfma_f32_32x32x16_f16(w2lo, h1lo, cinit, 0, 0, 0);
        d        = __builtin_amdgcn_mfma_f32_32x32x16_f16(w2hi, h1hi, d,     0, 0, 0);

        float partial = 0.f;
#pragma unroll
        for (int r = 0; r < 8; ++r)
            partial = fmaf(fmaxf(d[r], 0.f), w3r[r], partial);
        partial += __shfl_xor(partial, 32, 64);
        const float z = partial + b3v;
        float sim = __builtin_amdgcn_rcpf(1.f + __expf(-z));
        if (i == j) sim = 1.f;
        if (lane < 32) out[(size_t)i * NN + j] = sim;
    }
}

// ---------------------------------------------------------------------------
// PROBE (diagnostic, this round only): sim's hot loop replayed 16x.
// asm "+v" barrier on the pb fragments each rep defeats LICM (rule #17),
// so h1/MFMA/epilogue re-execute; result accumulated and written to d_ws.
// top-5 row for this kernel gives t_sim ~= dur/16 plus sim's real
// MfmaUtil/VALUBusy/Occupancy.
// ---------------------------------------------------------------------------
__global__ __launch_bounds__(256) void probe_kernel(
    const _Float16* __restrict__ pa, const _Float16* __restrict__ pb,
    const float* __restrict__ W2, const float* __restrict__ b2,
    const float* __restrict__ W3, const float* __restrict__ b3,
    float* __restrict__ pout)
{
    __shared__ _Float16 paLDS[32 * 32];
    const int t    = threadIdx.x;
    const int lane = t & 63;
    const int wid  = t >> 6;
    const int gwid = blockIdx.x * 4 + wid;
    const int i0 = (blockIdx.x >> 4) * 32;
    const int jb = (((blockIdx.x & 15) << 2) + wid) * 32;
    const int p  = lane & 31;
    const int g  = lane >> 5;

    ((uint2*)paLDS)[t] = ((const uint2*)(pa + (size_t)i0 * 32))[t];

    const _Float16* pbrow = pb + (size_t)(jb + p) * 32;
    f16x8 pblo = *(const f16x8*)(pbrow + g * 8);
    f16x8 pbhi = *(const f16x8*)(pbrow + 16 + g * 8);

    f16x8 w2lo = {};
    f16x8 w2hi = {};
    if (p < 16) {
        const float* w2r = W2 + p * 32;
#pragma unroll
        for (int e = 0; e < 8; ++e) {
            w2lo[e] = (_Float16)w2r[g * 8 + e];
            w2hi[e] = (_Float16)w2r[16 + g * 8 + e];
        }
    }

    float w3r[8];
    f32x16 cinit;
#pragma unroll
    for (int r = 0; r < 4; ++r) {
        w3r[r]       = W3[4 * g + r];
        w3r[4 + r]   = W3[8 + 4 * g + r];
        cinit[r]     = b2[4 * g + r];
        cinit[4 + r] = b2[8 + 4 * g + r];
    }
#pragma unroll
    for (int r = 8; r < 16; ++r) cinit[r] = 0.f;

    const float b3v = b3[0];
    const f16x8 zero = {};

    __syncthreads();

    float acc = 0.f;
    for (int rep = 0; rep < 16; ++rep) {
        f16x8 qlo = pblo, qhi = pbhi;
        asm volatile("" : "+v"(qlo), "+v"(qhi));   // defeat LICM across reps
#pragma unroll 4
        for (int ii = 0; ii < 32; ++ii) {
            f16x8 alo = *(const f16x8*)&paLDS[ii * 32 + g * 8];
            f16x8 ahi = *(const f16x8*)&paLDS[ii * 32 + 16 + g * 8];
            f16x8 h1lo = __builtin_elementwise_max(alo + qlo, zero);
            f16x8 h1hi = __builtin_elementwise_max(ahi + qhi, zero);

            f32x16 d = __builtin_amdgcn_mfma_f32_32x32x16_f16(w2lo, h1lo, cinit, 0, 0, 0);
            d        = __builtin_amdgcn_mfma_f32_32x32x16_f16(w2hi, h1hi, d,     0, 0, 0);

            float partial = 0.f;
#pragma unroll
            for (int r = 0; r < 8; ++r)
                partial = fmaf(fmaxf(d[r], 0.f), w3r[r], partial);
            partial += __shfl_xor(partial, 32, 64);
            const float z = partial + b3v;
            acc += __builtin_amdgcn_rcpf(1.f + __expf(-z));
        }
    }
    pout[(size_t)gwid * 64 + lane] = acc;
}

extern "C" void kernel_launch(void* const* d_in, const int* in_sizes, int n_in,
                              void* d_out, int out_size, void* d_ws, size_t ws_size,
                              hipStream_t stream)
{
    const float* A  = (const float*)d_in[0];
    const float* Wp = (const float*)d_in[1];
    const float* bp = (const float*)d_in[2];
    const float* W1 = (const float*)d_in[3];
    const float* b1 = (const float*)d_in[4];
    const float* W2 = (const float*)d_in[5];
    const float* b2 = (const float*)d_in[6];
    const float* W3 = (const float*)d_in[7];
    const float* b3 = (const float*)d_in[8];
    float* out = (float*)d_out;

    _Float16* pa = (_Float16*)d_ws;        // 2048*32 f16 = 128 KB
    _Float16* pb = pa + NN * 32;           // next 128 KB
    float* pout = (float*)((char*)d_ws + (32u << 20));  // probe scratch @ +32MB

    prep_kernel<<<NN / 8, 256, 0, stream>>>(A, Wp, bp, W1, b1, pa, pb);
    sim_kernel<<<1024, 256, 0, stream>>>(pa, pb, W2, b2, W3, b3, out);
    probe_kernel<<<1024, 256, 0, stream>>>(pa, pb, W2, b2, W3, b3, pout);
}

// Round 5
// 93.783 us; speedup vs baseline: 3.4623x; 3.4623x over previous
//
#include <hip/hip_runtime.h>
#include <hip/hip_fp16.h>

#define NN 2048

typedef _Float16 f16x8 __attribute__((ext_vector_type(8)));
typedef float f32x16 __attribute__((ext_vector_type(16)));

// ---------------------------------------------------------------------------
// Prep: proj = A@Wp.T + bp  (2048x32), then
//       pa'  = proj@Wa.T + b1  (f16, b1 folded),  pb = proj@Wb.T (f16)
// ---------------------------------------------------------------------------
__global__ __launch_bounds__(256) void prep_kernel(
    const float* __restrict__ A, const float* __restrict__ Wp,
    const float* __restrict__ bp, const float* __restrict__ W1,
    const float* __restrict__ b1,
    _Float16* __restrict__ pa, _Float16* __restrict__ pb)
{
    __shared__ float projLDS[8][32];
    const int t = threadIdx.x;
    const int rl = t >> 5;        // local row 0..7
    const int k  = t & 31;        // output unit 0..31
    const int row = blockIdx.x * 8 + rl;

    const float4* xa = (const float4*)(A + row * 64);
    const float4* wp = (const float4*)(Wp + k * 64);
    float acc = bp[k];
#pragma unroll
    for (int m = 0; m < 16; ++m) {
        float4 xv = xa[m], wv = wp[m];
        acc += xv.x * wv.x + xv.y * wv.y + xv.z * wv.z + xv.w * wv.w;
    }
    projLDS[rl][k] = acc;
    __syncthreads();

    const float4* w1a = (const float4*)(W1 + k * 64);        // m = 0..31
    const float4* w1b = (const float4*)(W1 + k * 64 + 32);   // m = 32..63
    const float4* pr  = (const float4*)(projLDS[rl]);
    float sa = b1[k], sb = 0.f;
#pragma unroll
    for (int m = 0; m < 8; ++m) {
        float4 p = pr[m], wa = w1a[m], wb = w1b[m];
        sa += p.x * wa.x + p.y * wa.y + p.z * wa.z + p.w * wa.w;
        sb += p.x * wb.x + p.y * wb.y + p.z * wb.z + p.w * wb.w;
    }
    pa[row * 32 + k] = (_Float16)sa;
    pb[row * 32 + k] = (_Float16)sb;
}

// ---------------------------------------------------------------------------
// Main: one wave owns a 16i x 32j output tile; 4 waves/block share the
// 16-row pa tile (1 KB LDS). Per iteration TWO i's (iA, iB=iA+1):
//   dX[h][pair] = W2(A, 32x16 rows, zero-padded) . h1X^T  via 2 chained
//   mfma_f32_32x32x16_f16 (k-halves), C preloaded with b2.
// After the shfl_xor(32) row-reduce BOTH wave halves hold each sum, so
// z = lane<32 ? pA : pB gives 64 unique outputs -> sigmoid + diag + store
// run FULL-WAVE with no exec masking (R4 probe: epilogue was half-masked
// and sim was VALU-issue-bound at 86% VALUBusy).
// D layout (verified m74/m101): col=lane&31, row=(r&3)+8*(r>>2)+4*(lane>>5).
// A/B per-lane k-permutation cancels (same (g,e)->k map on both operands).
// ---------------------------------------------------------------------------
__global__ __launch_bounds__(256, 4) void sim_kernel(
    const _Float16* __restrict__ pa, const _Float16* __restrict__ pb,
    const float* __restrict__ W2, const float* __restrict__ b2,
    const float* __restrict__ W3, const float* __restrict__ b3,
    float* __restrict__ out)
{
    __shared__ _Float16 paLDS[16 * 32];
    const int t    = threadIdx.x;
    const int lane = t & 63;
    const int wid  = t >> 6;                         // wave in block 0..3
    const int i0 = (blockIdx.x >> 4) * 16;           // 128 i-tiles of 16
    const int jb = (((blockIdx.x & 15) << 2) + wid) * 32;
    const int p  = lane & 31;                        // pair column within tile
    const int g  = lane >> 5;                        // k-group half / i-half

    // stage pa i-tile: 512 halves = 1KB, 4B per thread
    ((uint*)paLDS)[t] = ((const uint*)(pa + (size_t)i0 * 32))[t];

    // persistent pb fragment for this wave's 32 j's
    const _Float16* pbrow = pb + (size_t)(jb + p) * 32;
    f16x8 pblo = *(const f16x8*)(pbrow + g * 8);        // k = g*8 + e
    f16x8 pbhi = *(const f16x8*)(pbrow + 16 + g * 8);   // k = 16 + g*8 + e

    // W2 as A-operand: A[m][k], m = lane&31 (rows >= 16 zero-padded)
    f16x8 w2lo = {};
    f16x8 w2hi = {};
    if (p < 16) {
        const float* w2r = W2 + p * 32;
#pragma unroll
        for (int e = 0; e < 8; ++e) {
            w2lo[e] = (_Float16)w2r[g * 8 + e];
            w2hi[e] = (_Float16)w2r[16 + g * 8 + e];
        }
    }

    // per-lane W3 and b2(C-init) following the D row map
    float w3r[8];
    f32x16 cinit;
#pragma unroll
    for (int r = 0; r < 4; ++r) {
        w3r[r]       = W3[4 * g + r];
        w3r[4 + r]   = W3[8 + 4 * g + r];
        cinit[r]     = b2[4 * g + r];
        cinit[4 + r] = b2[8 + 4 * g + r];
    }
#pragma unroll
    for (int r = 8; r < 16; ++r) cinit[r] = 0.f;

    const float b3v = b3[0];
    const f16x8 zero = {};
    const int jlane = jb + p;                 // this lane's output column
    // per-lane output base: row parity g, column jlane
    float* outp = out + (size_t)g * NN + jlane;

    __syncthreads();

#pragma unroll 2
    for (int tt = 0; tt < 8; ++tt) {
        const int iA = i0 + 2 * tt;
        const _Float16* rowA = &paLDS[(2 * tt) * 32];
        const _Float16* rowB = &paLDS[(2 * tt + 1) * 32];
        f16x8 aAlo = *(const f16x8*)(rowA + g * 8);          // broadcast reads
        f16x8 aAhi = *(const f16x8*)(rowA + 16 + g * 8);
        f16x8 aBlo = *(const f16x8*)(rowB + g * 8);
        f16x8 aBhi = *(const f16x8*)(rowB + 16 + g * 8);
        f16x8 hAlo = __builtin_elementwise_max(aAlo + pblo, zero);
        f16x8 hAhi = __builtin_elementwise_max(aAhi + pbhi, zero);
        f16x8 hBlo = __builtin_elementwise_max(aBlo + pblo, zero);
        f16x8 hBhi = __builtin_elementwise_max(aBhi + pbhi, zero);

        f32x16 dA = __builtin_amdgcn_mfma_f32_32x32x16_f16(w2lo, hAlo, cinit, 0, 0, 0);
        f32x16 dB = __builtin_amdgcn_mfma_f32_32x32x16_f16(w2lo, hBlo, cinit, 0, 0, 0);
        dA        = __builtin_amdgcn_mfma_f32_32x32x16_f16(w2hi, hAhi, dA,    0, 0, 0);
        dB        = __builtin_amdgcn_mfma_f32_32x32x16_f16(w2hi, hBhi, dB,    0, 0, 0);

        // second layer: logit = sum_h relu(h2[h]) * W3[h]
        float pA = 0.f, pB = 0.f;
#pragma unroll
        for (int r = 0; r < 8; ++r) {
            pA = fmaf(fmaxf(dA[r], 0.f), w3r[r], pA);
            pB = fmaf(fmaxf(dB[r], 0.f), w3r[r], pB);
        }
        pA += __shfl_xor(pA, 32, 64);   // both halves now hold full sum
        pB += __shfl_xor(pB, 32, 64);

        // full-wave epilogue: lane half g picks its i (iA+g), column jlane
        const float z = (g == 0 ? pA : pB) + b3v;
        float sim = __builtin_amdgcn_rcpf(1.f + __expf(-z));
        if (iA + g == jlane) sim = 1.f;
        outp[(size_t)iA * NN] = sim;    // full-exec coalesced store
    }
}

extern "C" void kernel_launch(void* const* d_in, const int* in_sizes, int n_in,
                              void* d_out, int out_size, void* d_ws, size_t ws_size,
                              hipStream_t stream)
{
    const float* A  = (const float*)d_in[0];
    const float* Wp = (const float*)d_in[1];
    const float* bp = (const float*)d_in[2];
    const float* W1 = (const float*)d_in[3];
    const float* b1 = (const float*)d_in[4];
    const float* W2 = (const float*)d_in[5];
    const float* b2 = (const float*)d_in[6];
    const float* W3 = (const float*)d_in[7];
    const float* b3 = (const float*)d_in[8];
    float* out = (float*)d_out;

    _Float16* pa = (_Float16*)d_ws;        // 2048*32 f16 = 128 KB
    _Float16* pb = pa + NN * 32;           // next 128 KB

    prep_kernel<<<NN / 8, 256, 0, stream>>>(A, Wp, bp, W1, b1, pa, pb);
    sim_kernel<<<2048, 256, 0, stream>>>(pa, pb, W2, b2, W3, b3, out);
}